// Round 8
// baseline (5614.103 us; speedup 1.0000x reference)
//
#include <hip/hip_runtime.h>

// ResidualSkipRNNForecaster — R14: R13 (full-K-per-wave MFMA, no b1,
// shfl-reduce stats, R9-verbatim rendezvous) + HEAD FIX.
// R13 bug: head loop iterated 2 items/lane (32 lanes/chain) -> covered only
// blocks 0..7 = half the hidden dim. Fix: 4 items/lane, g = l32 + 32*it.

#define T_SZ 1024
#define DD   64
#define HH   512
#define NCH  8
#define NBLK 16

typedef __attribute__((ext_vector_type(8))) short short8;
typedef __attribute__((ext_vector_type(4))) float f32x4;
typedef unsigned long long ull;

__device__ __forceinline__ unsigned short f2b(float f) {
  unsigned u = __float_as_uint(f);
  u += 0x7fffu + ((u >> 16) & 1u);   // RNE
  return (unsigned short)(u >> 16);
}
__device__ __forceinline__ float b2f(unsigned short s) {
  return __uint_as_float(((unsigned)s) << 16);
}
__device__ __forceinline__ ull packf2(float a, float b) {
  return (ull)__float_as_uint(a) | ((ull)__float_as_uint(b) << 32);
}
__device__ __forceinline__ float unpack_lo(ull u) { return __uint_as_float((unsigned)u); }
__device__ __forceinline__ float unpack_hi(ull u) { return __uint_as_float((unsigned)(u >> 32)); }
__device__ __forceinline__ void st_rlx(ull* p, ull v) {
  __hip_atomic_store(p, v, __ATOMIC_RELAXED, __HIP_MEMORY_SCOPE_AGENT);
}
__device__ __forceinline__ ull ld_rlx(const ull* p) {
  return __hip_atomic_load(p, __ATOMIC_RELAXED, __HIP_MEMORY_SCOPE_AGENT);
}
__device__ __forceinline__ unsigned ld_flag(const unsigned* p) {
  return __hip_atomic_load(p, __ATOMIC_RELAXED, __HIP_MEMORY_SCOPE_AGENT);
}
__device__ __forceinline__ void st_flag(unsigned* p, unsigned v) {
  asm volatile("" ::: "memory");
  __hip_atomic_store(p, v, __ATOMIC_RELAXED, __HIP_MEMORY_SCOPE_AGENT);
}
__device__ __forceinline__ float fast_tanh(float z) {
  const float e = __builtin_amdgcn_exp2f(z * 2.885390081777927f);  // e^{2z}
  return 1.f - 2.f * __builtin_amdgcn_rcpf(e + 1.f);
}

__global__ void prep_kernel(const float* __restrict__ Wh0, const float* __restrict__ Wi1,
                            const float* __restrict__ Wh1,
                            const float* __restrict__ bi0, const float* __restrict__ bh0,
                            const float* __restrict__ bi1, const float* __restrict__ bh1,
                            const float* __restrict__ g0, const float* __restrict__ be0,
                            const float* __restrict__ g1, const float* __restrict__ be1,
                            float* __restrict__ cvec, unsigned* __restrict__ flags) {
  int g = blockIdx.x * blockDim.x + threadIdx.x;
  if (g < HH) {
    float uw0 = 0.f, qw0 = 0.f, uw1 = 0.f, qw1 = 0.f, uh1 = 0.f, qh1 = 0.f;
    for (int j = 0; j < HH; ++j) {
      float a = Wh0[j * HH + g], b = Wi1[j * HH + g], d = Wh1[j * HH + g];
      uw0 += g0[j] * a; qw0 += be0[j] * a;
      uw1 += g0[j] * b; qw1 += be0[j] * b;
      uh1 += g1[j] * d; qh1 += be1[j] * d;
    }
    float b0 = bi0[g] + bh0[g], b1 = bi1[g] + bh1[g];
    cvec[0 * HH + g] = b0 + qw0;        // c0 full (t>0)
    cvec[1 * HH + g] = b0;              // c0 init (t==0)
    cvec[2 * HH + g] = b1 + qw1 + qh1;  // c1 full
    cvec[3 * HH + g] = b1 + qw1;        // c1 init
    cvec[4 * HH + g] = uw0;
    cvec[5 * HH + g] = uw1;
    cvec[6 * HH + g] = uh1;
  }
  if (g < 4096) flags[g] = 0;           // 256 blocks x 16 words (flag at +0)
}

// pc layout: [blk][L][par][80 ull]: words 0..63 = pay (8 ch x 8 words, word w
// = cols 4w..4w+3 of the block's 32), words 64..79 = stats (8 ch x 2 tiles).
__global__ __launch_bounds__(256, 1) void rnn_mfma(
    const float* __restrict__ x,
    const float* __restrict__ Wi0, const float* __restrict__ Wh0,
    const float* __restrict__ Wi1, const float* __restrict__ Wh1,
    const float* __restrict__ cvec,
    const float* __restrict__ g0v, const float* __restrict__ be0v,
    const float* __restrict__ g1v, const float* __restrict__ be1v,
    const float* __restrict__ wfc, const float* __restrict__ bfc,
    ull* __restrict__ pc, unsigned* __restrict__ flags,
    float* __restrict__ out) {

  const int blk = blockIdx.x, group = blk >> 4, p = blk & 15;
  const int tid = threadIdx.x;
  const int wave = tid >> 6, lane = tid & 63;
  const int quad = lane >> 4, m16 = lane & 15;
  const int tile = wave & 1, role = wave >> 1;       // role 0 = L0, 1 = L1

  __shared__ unsigned short a0bf[16][536];   // bf16 v2_0^{s-1} (rows 8..15 = 0)
  __shared__ unsigned short a1bf[16][536];   // bf16 v2_1^{s-2}
  __shared__ unsigned short xsb[16][72];     // bf16 x_s (rows 8..15 = 0)
  __shared__ float2 st0[NCH][32];            // (S,Q) partials: [ch][blk*2+tile]
  __shared__ float2 st1[NCH][32];

  // ---------------- init ----------------
  for (int i = tid; i < 16 * 536; i += 256) {
    (&a0bf[0][0])[i] = 0; (&a1bf[0][0])[i] = 0;
  }
  for (int i = tid; i < 16 * 72; i += 256) (&xsb[0][0])[i] = 0;
  if (tid < NCH * 32) {
    (&st0[0][0])[tid] = make_float2(0.f, 0.f);
    (&st1[0][0])[tid] = make_float2(0.f, 0.f);
  }
  { // x_0: thread -> (chain=tid>>5, 2 dims)
    const int ch = tid >> 5, d = (tid & 31) * 2;
    const float2 xv = *(const float2*)&x[((size_t)(group * NCH + ch) * T_SZ) * DD + d];
    xsb[ch][d] = f2b(xv.x); xsb[ch][d + 1] = f2b(xv.y);
  }

  // ---------------- static weight B-fragments (full K=512 per wave) -------
  const int colw = p * 32 + tile * 16 + m16;
  short8 wA[16], wB2[16], wX[2];
#pragma unroll
  for (int n = 0; n < 2; ++n)
#pragma unroll
    for (int j = 0; j < 8; ++j) wX[n][j] = 0;
#pragma unroll
  for (int ks = 0; ks < 16; ++ks)
#pragma unroll
    for (int j = 0; j < 8; ++j) {
      const int k = ks * 32 + quad * 8 + j;
      if (role == 0) {
        wA[ks][j]  = (short)f2b(g0v[k] * Wh0[(size_t)k * HH + colw]);
        wB2[ks][j] = 0;
      } else {
        wA[ks][j]  = (short)f2b(g0v[k] * Wi1[(size_t)k * HH + colw]);
        wB2[ks][j] = (short)f2b(g1v[k] * Wh1[(size_t)k * HH + colw]);
      }
    }
  if (role == 0)
#pragma unroll
    for (int ks = 0; ks < 2; ++ks)
#pragma unroll
      for (int j = 0; j < 8; ++j)
        wX[ks][j] = (short)f2b(Wi0[(size_t)(ks * 32 + quad * 8 + j) * HH + colw]);

  // epilogue constants (role-selected, per output col)
  const float cIc = role ? cvec[3 * HH + colw] : cvec[HH + colw];
  const float cFc = role ? cvec[2 * HH + colw] : cvec[0 * HH + colw];
  const float uA  = role ? cvec[5 * HH + colw] : cvec[4 * HH + colw];
  const float uB  = role ? cvec[6 * HH + colw] : 0.f;
  const float gC  = role ? g1v[colw] : g0v[colw];
  const float beC = role ? be1v[colw] : be0v[colw];

  ull* const pubbase = pc + ((size_t)(blk * 2 + role) * 2 + 0) * 80;  // + par*80
  unsigned short (*abSelf)[536] = role ? a1bf : a0bf;
  float2 (*stSelf)[32] = role ? st1 : st0;

  // gather: wave w -> peers 4w..4w+npeers-1 (15 total)
  const int npeers = (wave < 3) ? 4 : 3;
  const int pollj = wave * 4 + lane;
  const int pollpl = pollj + (pollj >= p);
  const unsigned* pollflag = flags + (group * NBLK + ((lane < npeers) ? pollpl : 0)) * 16;

  const ull* gsrc[10]; ull* gdst[10]; unsigned gvm = 0, gl0 = 0;
#pragma unroll
  for (int k = 0; k < 10; ++k) {
    const int li = lane + (k << 6);
    const bool v = li < npeers * 160;
    const int li2 = v ? li : 0;
    const int pj = wave * 4 + li2 / 160, r2 = li2 % 160;
    const int pl = pj + (pj >= p);
    const int L = r2 / 80, rr = r2 % 80;
    gsrc[k] = pc + ((size_t)((group * NBLK + pl) * 2 + L) * 2 + 0) * 80 + rr;
    if (rr < 64) {
      const int ch = rr >> 3, w = rr & 7;
      gdst[k] = (ull*)&(L ? a1bf : a0bf)[ch][pl * 32 + w * 4];
    } else {
      const int e = rr - 64;
      gdst[k] = (ull*)&(L ? st1 : st0)[e >> 1][pl * 2 + (e & 1)];
    }
    if (v) gvm |= 1u << k;
    if (L == 0) gl0 |= 1u << k;
  }

  const float* xptr = x + ((size_t)(group * NCH + (tid >> 5)) * T_SZ + 1) * DD + (tid & 31) * 2;

  float v2p[4] = {0.f, 0.f, 0.f, 0.f};
  __syncthreads();

  for (int s = 0; s <= T_SZ; ++s) {
    const int par = s & 1;
    const int partw = par * 80;

    // ---- hoisted LN stats: shfl-reduce (st sealed by prev b3) ----
    float mA[4], rA[4], mB[4], rB[4];
    {
      float S = 0.f, Q = 0.f;
      if (s > 0) {
#pragma unroll
        for (int i = 0; i < 4; ++i) {
          float2 e = st0[lane >> 3][(lane & 7) * 4 + i]; S += e.x; Q += e.y;
        }
      }
      S += __shfl_xor(S, 1); Q += __shfl_xor(Q, 1);
      S += __shfl_xor(S, 2); Q += __shfl_xor(Q, 2);
      S += __shfl_xor(S, 4); Q += __shfl_xor(Q, 4);
      const float m = S * (1.f / HH);
      const float r = (s > 0) ? __builtin_amdgcn_rsqf(Q * (1.f / HH) - m * m + 1e-5f) : 0.f;
#pragma unroll
      for (int r_ = 0; r_ < 4; ++r_) {
        const int src = (((quad * 4 + r_) & 7) << 3);
        mA[r_] = __shfl(m, src); rA[r_] = __shfl(r, src);
      }
      if (role == 1) {
        float S1 = 0.f, Q1 = 0.f;
        if (s > 1) {
#pragma unroll
          for (int i = 0; i < 4; ++i) {
            float2 e = st1[lane >> 3][(lane & 7) * 4 + i]; S1 += e.x; Q1 += e.y;
          }
        }
        S1 += __shfl_xor(S1, 1); Q1 += __shfl_xor(Q1, 1);
        S1 += __shfl_xor(S1, 2); Q1 += __shfl_xor(Q1, 2);
        S1 += __shfl_xor(S1, 4); Q1 += __shfl_xor(Q1, 4);
        const float m1 = S1 * (1.f / HH);
        const float r1 = (s > 1) ? __builtin_amdgcn_rsqf(Q1 * (1.f / HH) - m1 * m1 + 1e-5f) : 0.f;
#pragma unroll
        for (int r_ = 0; r_ < 4; ++r_) {
          const int src = (((quad * 4 + r_) & 7) << 3);
          mB[r_] = __shfl(m1, src); rB[r_] = __shfl(r1, src);
        }
      } else {
#pragma unroll
        for (int r_ = 0; r_ < 4; ++r_) { mB[r_] = 0.f; rB[r_] = 0.f; }
      }
    }

    // ---- MFMA: full-K per wave, private accs (2-way interleave) ----
    f32x4 ac0 = {0.f,0.f,0.f,0.f}, ac1 = {0.f,0.f,0.f,0.f};
    f32x4 ac2 = {0.f,0.f,0.f,0.f}, ac3 = {0.f,0.f,0.f,0.f};
    if (role == 0) {
#pragma unroll
      for (int ks = 0; ks < 16; ++ks) {
        const short8 af = *(const short8*)&a0bf[m16][ks * 32 + quad * 8];
        if (ks & 1) ac1 = __builtin_amdgcn_mfma_f32_16x16x32_bf16(af, wA[ks], ac1, 0, 0, 0);
        else        ac0 = __builtin_amdgcn_mfma_f32_16x16x32_bf16(af, wA[ks], ac0, 0, 0, 0);
      }
      const short8 xf0 = *(const short8*)&xsb[m16][quad * 8];
      const short8 xf1 = *(const short8*)&xsb[m16][32 + quad * 8];
      ac2 = __builtin_amdgcn_mfma_f32_16x16x32_bf16(xf0, wX[0], ac2, 0, 0, 0);
      ac2 = __builtin_amdgcn_mfma_f32_16x16x32_bf16(xf1, wX[1], ac2, 0, 0, 0);
    } else {
#pragma unroll
      for (int ks = 0; ks < 16; ++ks) {
        const short8 af0 = *(const short8*)&a0bf[m16][ks * 32 + quad * 8];
        const short8 af1 = *(const short8*)&a1bf[m16][ks * 32 + quad * 8];
        if (ks & 1) {
          ac1 = __builtin_amdgcn_mfma_f32_16x16x32_bf16(af0, wA[ks],  ac1, 0, 0, 0);
          ac3 = __builtin_amdgcn_mfma_f32_16x16x32_bf16(af1, wB2[ks], ac3, 0, 0, 0);
        } else {
          ac0 = __builtin_amdgcn_mfma_f32_16x16x32_bf16(af0, wA[ks],  ac0, 0, 0, 0);
          ac2 = __builtin_amdgcn_mfma_f32_16x16x32_bf16(af1, wB2[ks], ac2, 0, 0, 0);
        }
      }
    }
    f32x4 accA, accB;
#pragma unroll
    for (int r_ = 0; r_ < 4; ++r_) {
      accA[r_] = ac0[r_] + ac1[r_];
      accB[r_] = (role == 0) ? ac2[r_] : (ac2[r_] + ac3[r_]);
    }

    // ---- epilogue (private accs; publish global; LDS writes deferred) ----
    const bool act = role ? (s >= 1) : (s < T_SZ);
    unsigned vbr[4]; float myS[4], myQ[4];
    if (act) {
      const bool first = role ? (s == 1) : (s == 0);
      const float cF = first ? cIc : cFc;
#pragma unroll
      for (int r_ = 0; r_ < 4; ++r_) {
        float z = cF + rA[r_] * accA[r_] - rA[r_] * mA[r_] * uA;
        if (role == 0) z += accB[r_];
        else           z += rB[r_] * accB[r_] - rB[r_] * mB[r_] * uB;
        const float mP = role ? mB[r_] : mA[r_];
        const float rP = role ? rB[r_] : rA[r_];
        const float hprev = first ? 0.f : (v2p[r_] - mP) * rP * gC + beC;
        const float v2 = fast_tanh(z) + hprev;
        v2p[r_] = v2;
        const unsigned vb = f2b(v2);
        vbr[r_] = vb;
        const unsigned u01 = vb | (__shfl_down(vb, 1) << 16);
        const ull word = (ull)u01 | ((ull)__shfl_down(u01, 2) << 32);
        if (quad < 2 && (m16 & 3) == 0)
          st_rlx(pubbase + partw + (quad * 4 + r_) * 8 + tile * 4 + (m16 >> 2), word);
        float S = v2, Q = v2 * v2;
        S += __shfl_xor(S, 1); Q += __shfl_xor(Q, 1);
        S += __shfl_xor(S, 2); Q += __shfl_xor(Q, 2);
        S += __shfl_xor(S, 4); Q += __shfl_xor(Q, 4);
        S += __shfl_xor(S, 8); Q += __shfl_xor(Q, 8);
        myS[r_] = S; myQ[r_] = Q;
        if (quad < 2 && m16 == 0)
          st_rlx(pubbase + partw + 64 + (quad * 4 + r_) * 2 + tile, packf2(S, Q));
      }
    }

    __syncthreads();                                  // b2 (drains publishes)
    if (tid == 0) st_flag(flags + blk * 16, (unsigned)(s + 1));
    if (s == T_SZ) break;

    // x prefetch issue (latency hidden under poll+gather)
    float2 xv = make_float2(0.f, 0.f);
    if (s + 1 < T_SZ) xv = *(const float2*)xptr;
    xptr += DD;

    // deferred LDS self-writes (sealed by b3 before next slot's reads)
    if (act && quad < 2) {
#pragma unroll
      for (int r_ = 0; r_ < 4; ++r_)
        abSelf[quad * 4 + r_][p * 32 + tile * 16 + m16] = (unsigned short)vbr[r_];
      if (m16 == 0) {
#pragma unroll
        for (int r_ = 0; r_ < 4; ++r_)
          stSelf[quad * 4 + r_][p * 2 + tile] = make_float2(myS[r_], myQ[r_]);
      }
    }

    // poll this wave's peers (R9-style exec-mask loop)
    if (lane < npeers)
      while (ld_flag(pollflag) < (unsigned)(s + 1)) __builtin_amdgcn_s_sleep(1);

    // register-staged gather: 10 loads then 10 8B LDS stores
    {
      ull tv[10];
#pragma unroll
      for (int k = 0; k < 10; ++k) {
        const bool v = ((gvm >> k) & 1u) && (s > 0 || ((gl0 >> k) & 1u));
        tv[k] = 0;
        if (v) tv[k] = ld_rlx(gsrc[k] + partw);
      }
#pragma unroll
      for (int k = 0; k < 10; ++k) {
        const bool v = ((gvm >> k) & 1u) && (s > 0 || ((gl0 >> k) & 1u));
        if (v) *gdst[k] = tv[k];
      }
    }
    if (s + 1 < T_SZ) {
      const int ch = tid >> 5, d = (tid & 31) * 2;
      *(unsigned*)&xsb[ch][d] = (unsigned)f2b(xv.x) | ((unsigned)f2b(xv.y) << 16);
    }
    __syncthreads();                                  // b3
  }

  // ============ head (p==0 blocks): out = LN(v2_1^{T-1}).Wfc + bfc ========
  // v2_1^{T-1} published at slot T (par=0), covered by flag T+1.
  if (p == 0) {
    if (tid < 15) {
      const unsigned* pf = flags + (group * NBLK + tid + 1) * 16;
      while (ld_flag(pf) < (unsigned)(T_SZ + 1)) __builtin_amdgcn_s_sleep(2);
    }
    __syncthreads();
    const int half = lane >> 5, l32 = lane & 31;
    const int c = wave * 2 + half;                    // chain 0..7
    // stats: 32 entries (16 blocks x 2 tiles)
    ull su = ld_rlx(pc + ((size_t)((group * NBLK + (l32 >> 1)) * 2 + 1) * 2 + 0) * 80
                       + 64 + c * 2 + (l32 & 1));
    float S = unpack_lo(su), Q = unpack_hi(su);
#pragma unroll
    for (int off = 16; off; off >>= 1) {
      S += __shfl_down(S, off, 32); Q += __shfl_down(Q, off, 32);
    }
    S = __shfl(S, lane & 32); Q = __shfl(Q, lane & 32);
    const float m1 = S * (1.f / HH);
    const float r1 = __builtin_amdgcn_rsqf(Q * (1.f / HH) - m1 * m1 + 1e-5f);
    float o = 0.f;
#pragma unroll
    for (int it = 0; it < 4; ++it) {                  // FIX: 4 items x 32 lanes
      const int g = l32 + (it << 5);                  // g in [0,128): all 16 blocks
      const int bl = g >> 3, w = g & 7;
      const ull u = ld_rlx(pc + ((size_t)((group * NBLK + bl) * 2 + 1) * 2 + 0) * 80 + c * 8 + w);
#pragma unroll
      for (int qq = 0; qq < 4; ++qq) {
        const int col = bl * 32 + w * 4 + qq;
        o += ((b2f((unsigned short)(u >> (16 * qq))) - m1) * r1 * g1v[col] + be1v[col]) * wfc[col];
      }
    }
#pragma unroll
    for (int off = 16; off; off >>= 1) o += __shfl_down(o, off, 32);
    if (l32 == 0) out[group * NCH + c] = o + bfc[0];
  }
}

extern "C" void kernel_launch(void* const* d_in, const int* in_sizes, int n_in,
                              void* d_out, int out_size, void* d_ws, size_t ws_size,
                              hipStream_t stream) {
  const float* x   = (const float*)d_in[0];
  const float* Wi0 = (const float*)d_in[1];
  const float* bi0 = (const float*)d_in[2];
  const float* Wh0 = (const float*)d_in[3];
  const float* bh0 = (const float*)d_in[4];
  const float* g0  = (const float*)d_in[5];
  const float* be0 = (const float*)d_in[6];
  const float* Wi1 = (const float*)d_in[7];
  const float* bi1 = (const float*)d_in[8];
  const float* Wh1 = (const float*)d_in[9];
  const float* bh1 = (const float*)d_in[10];
  const float* g1  = (const float*)d_in[11];
  const float* be1 = (const float*)d_in[12];
  const float* Wfc = (const float*)d_in[13];
  const float* bfc = (const float*)d_in[14];
  float* out = (float*)d_out;

  // ws: cvec 16KB | pc 640KB (256 blk x 2 L x 2 par x 80 ull) | flags 16KB
  char* ws = (char*)d_ws;
  float* cvec     = (float*)(ws);
  ull* pc         = (ull*)(ws + 16384);
  unsigned* flags = (unsigned*)(ws + 16384 + 655360);

  prep_kernel<<<256, 256, 0, stream>>>(Wh0, Wi1, Wh1, bi0, bh0, bi1, bh1,
                                       g0, be0, g1, be1, cvec, flags);
  rnn_mfma<<<256, 256, 0, stream>>>(x, Wi0, Wh0, Wi1, Wh1, cvec,
                                    g0, be0, g1, be1, Wfc, bfc,
                                    pc, flags, out);
}

// Round 10
// 4565.566 us; speedup vs baseline: 1.2297x; 1.2297x over previous
//
#include <hip/hip_runtime.h>

// ResidualSkipRNNForecaster — R16: R11 (self-tagged payload words, no flags,
// 2 barriers/slot — PASSING kernel) with the ONE fix its counters demanded:
// the gather retry loop is burst-pipelined.
//
// R11 post-mortem: each ld_rlx was immediately tag-checked -> compiler emits
// load; s_waitcnt vmcnt(0); cmp PER WORD -> up to 7 serialized MALL round
// trips per retry round (~2.8us). R16 loop: issue ALL needed loads (they
// pipeline, one exposed RT), then check tags, consume arrivals into LDS,
// re-issue only misses, s_sleep(1) between rounds.
// R15 (XCD/sc0) post-mortem: hung — correctness rested on an unverified
// dispatch-mapping assumption. Reverted; back to agent-scope atomics whose
// correctness is mapping-independent.
//
// Protocol (unchanged from R11): pay word = 3x bf16 | tag16(s+1)<<48 (11
// words/row), stat word = f32 | tag32(s+1)<<32. Readers poll the single
// shared copy until tag==s+1; stale parity-buffer data has tag s-1. Parity-2
// buffers + skew<=1 induction: our slot-s gather completing required every
// peer's tag-(s+1) words, published after that peer finished ITS slot-(s-1)
// gather => no peer can still be reading parity par(s) when we overwrite at
// slot s+2. Monotone tags => no ABA, no deadlock.

#define T_SZ 1024
#define DD   64
#define HH   512
#define NCH  8
#define NBLK 16
#define SENT 0xFFFFFFFFFFFFFFFFull
#define PAYW 104                       // words per (blk,L,par): 8 ch x 13
#define TOTW (256 * 2 * 2 * PAYW)      // 106496 words = 852KB

typedef __attribute__((ext_vector_type(8))) short short8;
typedef __attribute__((ext_vector_type(4))) float f32x4;
typedef unsigned long long ull;

__device__ __forceinline__ unsigned short f2b(float f) {
  unsigned u = __float_as_uint(f);
  u += 0x7fffu + ((u >> 16) & 1u);   // RNE
  return (unsigned short)(u >> 16);
}
__device__ __forceinline__ float b2f(unsigned short s) {
  return __uint_as_float(((unsigned)s) << 16);
}
__device__ __forceinline__ ull packf2(float a, float b) {
  return (ull)__float_as_uint(a) | ((ull)__float_as_uint(b) << 32);
}
__device__ __forceinline__ void st_rlx(ull* p, ull v) {
  __hip_atomic_store(p, v, __ATOMIC_RELAXED, __HIP_MEMORY_SCOPE_AGENT);
}
__device__ __forceinline__ ull ld_rlx(const ull* p) {
  return __hip_atomic_load(p, __ATOMIC_RELAXED, __HIP_MEMORY_SCOPE_AGENT);
}
// tanh(z) = 1 - 2/(e^{2z}+1), exact; exp2+rcp HW approx (~1e-7 abs err).
__device__ __forceinline__ float fast_tanh(float z) {
  const float e = __builtin_amdgcn_exp2f(z * 2.885390081777927f);  // e^{2z}
  return 1.f - 2.f * __builtin_amdgcn_rcpf(e + 1.f);
}

__global__ void prep_kernel(const float* __restrict__ Wh0, const float* __restrict__ Wi1,
                            const float* __restrict__ Wh1,
                            const float* __restrict__ bi0, const float* __restrict__ bh0,
                            const float* __restrict__ bi1, const float* __restrict__ bh1,
                            const float* __restrict__ g0, const float* __restrict__ be0,
                            const float* __restrict__ g1, const float* __restrict__ be1,
                            float* __restrict__ cvec, ull* __restrict__ pay) {
  int g = blockIdx.x * blockDim.x + threadIdx.x;
  if (g < HH) {
    float uw0 = 0.f, qw0 = 0.f, uw1 = 0.f, qw1 = 0.f, uh1 = 0.f, qh1 = 0.f;
    for (int j = 0; j < HH; ++j) {
      float a = Wh0[j * HH + g], b = Wi1[j * HH + g], d = Wh1[j * HH + g];
      uw0 += g0[j] * a; qw0 += be0[j] * a;
      uw1 += g0[j] * b; qw1 += be0[j] * b;
      uh1 += g1[j] * d; qh1 += be1[j] * d;
    }
    float b0 = bi0[g] + bh0[g], b1 = bi1[g] + bh1[g];
    cvec[0 * HH + g] = b0 + qw0;        // c0 full (t>0)
    cvec[1 * HH + g] = b0;              // c0 init (t==0)
    cvec[2 * HH + g] = b1 + qw1 + qh1;  // c1 full
    cvec[3 * HH + g] = b1 + qw1;        // c1 init
    cvec[4 * HH + g] = uw0;
    cvec[5 * HH + g] = uw1;
    cvec[6 * HH + g] = uh1;
  }
  const int base = g * 2;               // 65536 threads x 2 >= TOTW
#pragma unroll
  for (int i = 0; i < 2; ++i)
    if (base + i < TOTW) pay[base + i] = SENT;   // tag fields = 0xFFFF/0xFFFFFFFF
}

__global__ __launch_bounds__(512, 1) void rnn_mfma(
    const float* __restrict__ x,
    const float* __restrict__ Wi0, const float* __restrict__ Wh0,
    const float* __restrict__ Wi1, const float* __restrict__ Wh1,
    const float* __restrict__ cvec,
    const float* __restrict__ g0v, const float* __restrict__ be0v,
    const float* __restrict__ g1v, const float* __restrict__ be1v,
    const float* __restrict__ wfc, const float* __restrict__ bfc,
    ull* __restrict__ pay, float* __restrict__ out) {

  const int blk = blockIdx.x, group = blk >> 4, p = blk & 15;
  const int tid = threadIdx.x;
  const int wave = tid >> 6, lane = tid & 63;
  const int quad = lane >> 4, m16 = lane & 15;

  // row stride 536 bf16 = 268 words: 16B-aligned rows, banks spread (268%32=12)
  __shared__ unsigned short a0bf[16][536];   // bf16 v2_0^{s-1} (rows 8..15 = 0)
  __shared__ unsigned short a1bf[16][536];   // bf16 v2_1^{s-2}
  __shared__ unsigned short xsb[16][72];     // bf16 x_s (rewritten after b1)
  __shared__ float partsA[8][8][33];         // v2_0^{s-1} @ (g0.*Wh0)
  __shared__ float partsB[8][8][33];         // v2_1^{s-2} @ (g1.*Wh1)
  __shared__ float partsC[8][8][33];         // v2_0^{s-1} @ (g0.*Wi1)
  __shared__ float partsX[2][8][33];         // x_s @ Wi0 (waves 0,1)
  __shared__ float2 st0[NCH][NBLK];          // (S,Q) of v2_0^{s-1} per publisher
  __shared__ float2 st1[NCH][NBLK];          // (S,Q) of v2_1^{s-2}

  // ---------------- init ----------------
  for (int i = tid; i < 16 * 536; i += 512) {
    (&a0bf[0][0])[i] = 0; (&a1bf[0][0])[i] = 0;
  }
  for (int i = tid; i < 16 * 72; i += 512) (&xsb[0][0])[i] = 0;
  if (tid < NCH * NBLK) {
    (&st0[0][0])[tid] = make_float2(0.f, 0.f);
    (&st1[0][0])[tid] = make_float2(0.f, 0.f);
  }
  { // x_0: thread (wave=chain, lane=d)
    float xv = x[((size_t)(group * NCH + wave) * T_SZ) * DD + lane];
    xsb[wave][lane] = f2b(xv);
  }

  // ---------------- static weight B-fragments (bf16, gamma-folded) --------
  short8 wf0[2][2], wfA[2][2], wfB[2][2], wfx[2];
#pragma unroll
  for (int n = 0; n < 2; ++n)
#pragma unroll
    for (int j = 0; j < 8; ++j) wfx[n][j] = 0;
#pragma unroll
  for (int sl = 0; sl < 2; ++sl)
#pragma unroll
    for (int n = 0; n < 2; ++n) {
      const int col = p * 32 + n * 16 + m16;
#pragma unroll
      for (int j = 0; j < 8; ++j) {
        const int k = wave * 64 + sl * 32 + quad * 8 + j;
        wf0[sl][n][j] = (short)f2b(g0v[k] * Wh0[(size_t)k * HH + col]);
        wfA[sl][n][j] = (short)f2b(g0v[k] * Wi1[(size_t)k * HH + col]);
        wfB[sl][n][j] = (short)f2b(g1v[k] * Wh1[(size_t)k * HH + col]);
      }
    }
  if (wave < 2) {
#pragma unroll
    for (int n = 0; n < 2; ++n) {
      const int col = p * 32 + n * 16 + m16;
#pragma unroll
      for (int j = 0; j < 8; ++j)
        wfx[n][j] = (short)f2b(Wi0[(size_t)(wave * 32 + quad * 8 + j) * HH + col]);
    }
  }

  // epilogue constants — loaded by ALL threads (both wave halves need them)
  const int cl    = lane & 31;
  const int ech   = ((wave & 3) << 1) + (lane >> 5);   // chain 0..7 in each half
  const int col_e = p * 32 + cl;
  const float c0f = cvec[col_e],          c0i = cvec[HH + col_e];
  const float c1f = cvec[2 * HH + col_e], c1i = cvec[3 * HH + col_e];
  const float uw0 = cvec[4 * HH + col_e], uw1 = cvec[5 * HH + col_e];
  const float uh1 = cvec[6 * HH + col_e];
  const float g0c = g0v[col_e], be0c = be0v[col_e];
  const float g1c = g1v[col_e], be1c = be1v[col_e];

  // publisher plan: row base for this thread's (layer-half, chain-row)
  const int Lp = (wave >= 4) ? 1 : 0;
  ull* const prow0 = pay + (((size_t)blk * 2 + Lp) * 2 + 0) * PAYW + ech * 13;
  ull* const prow1 = prow0 + PAYW;
  const bool ispub = (cl % 3 == 0);        // lanes cl = 0,3,...,30 (11 per half)
  const int  jw    = cl / 3;               // word index 0..10
  unsigned short* const ep_lds = &((wave < 4) ? a0bf : a1bf)[ech][p * 32 + cl];

  // -------- gather plan: 3120 items = 15 peers x 2L x 8ch x 13w ----------
  const ull* gsrc[7]; void* gdst[7]; int gtype[7]; bool gL1[7];
#pragma unroll
  for (int k = 0; k < 7; ++k) {
    const int idx   = tid + (k << 9);
    const bool valid = idx < 15 * 208;
    const int cidx  = valid ? idx : 0;
    const int pi = cidx / 208, r = cidx - pi * 208;
    const int pl = pi + (pi >= p);
    const int L  = r / 104, rr = r - L * 104;
    const int ch = rr / 13, w = rr - ch * 13;
    gsrc[k] = pay + (((size_t)(group * NBLK + pl) * 2 + L) * 2 + 0) * PAYW + ch * 13 + w;
    gL1[k]  = (L == 1);
    if (!valid) { gtype[k] = 255; gdst[k] = (void*)&a0bf[0][0]; }
    else if (w < 11) {
      gtype[k] = (w == 10) ? 1 : 0;
      gdst[k] = (void*)&(L ? a1bf : a0bf)[ch][pl * 32 + 3 * w];
    } else {
      gtype[k] = 2;
      gdst[k] = (w == 11) ? (void*)&(L ? st1 : st0)[ch][pl].x
                          : (void*)&(L ? st1 : st0)[ch][pl].y;
    }
  }

  const float* xptr = x + ((size_t)(group * NCH + wave) * T_SZ + 1) * DD + lane;

  float v2prev0 = 0.f, v2prev1 = 0.f;
  __syncthreads();

  for (int s = 0; s <= T_SZ; ++s) {
    const int par = s & 1;
    const unsigned et = (unsigned)(s + 1);

    // ---- hoisted LN stats (st0/st1 sealed by prev b3, stable till gather) --
    float m0 = 0.f, r0 = 0.f, m1p = 0.f, r1p = 0.f;
    if (s > 0) {
      float S = 0.f, Q = 0.f;
#pragma unroll
      for (int i = 0; i < NBLK; ++i) { float2 sq = st0[ech][i]; S += sq.x; Q += sq.y; }
      m0 = S * (1.f / HH);
      r0 = __builtin_amdgcn_rsqf(Q * (1.f / HH) - m0 * m0 + 1e-5f);
    }
    if (wave >= 4 && s > 1) {
      float S = 0.f, Q = 0.f;
#pragma unroll
      for (int i = 0; i < NBLK; ++i) { float2 sq = st1[ech][i]; S += sq.x; Q += sq.y; }
      m1p = S * (1.f / HH);
      r1p = __builtin_amdgcn_rsqf(Q * (1.f / HH) - m1p * m1p + 1e-5f);
    }

    // ================= phase 1 : ALL MFMAs (operands from slot s-1) ========
    {
      f32x4 aA0 = {0.f,0.f,0.f,0.f}, aA1 = {0.f,0.f,0.f,0.f};
      f32x4 aB0 = {0.f,0.f,0.f,0.f}, aB1 = {0.f,0.f,0.f,0.f};
      f32x4 aC0 = {0.f,0.f,0.f,0.f}, aC1 = {0.f,0.f,0.f,0.f};
#pragma unroll
      for (int sl = 0; sl < 2; ++sl) {
        const short8 af0 = *(const short8*)&a0bf[m16][wave * 64 + sl * 32 + quad * 8];
        const short8 af1 = *(const short8*)&a1bf[m16][wave * 64 + sl * 32 + quad * 8];
        aA0 = __builtin_amdgcn_mfma_f32_16x16x32_bf16(af0, wf0[sl][0], aA0, 0, 0, 0);
        aA1 = __builtin_amdgcn_mfma_f32_16x16x32_bf16(af0, wf0[sl][1], aA1, 0, 0, 0);
        aC0 = __builtin_amdgcn_mfma_f32_16x16x32_bf16(af0, wfA[sl][0], aC0, 0, 0, 0);
        aC1 = __builtin_amdgcn_mfma_f32_16x16x32_bf16(af0, wfA[sl][1], aC1, 0, 0, 0);
        aB0 = __builtin_amdgcn_mfma_f32_16x16x32_bf16(af1, wfB[sl][0], aB0, 0, 0, 0);
        aB1 = __builtin_amdgcn_mfma_f32_16x16x32_bf16(af1, wfB[sl][1], aB1, 0, 0, 0);
      }
      if (lane < 32) {
#pragma unroll
        for (int r = 0; r < 4; ++r) {
          partsA[wave][quad * 4 + r][m16]      = aA0[r];
          partsA[wave][quad * 4 + r][16 + m16] = aA1[r];
          partsB[wave][quad * 4 + r][m16]      = aB0[r];
          partsB[wave][quad * 4 + r][16 + m16] = aB1[r];
          partsC[wave][quad * 4 + r][m16]      = aC0[r];
          partsC[wave][quad * 4 + r][16 + m16] = aC1[r];
        }
      }
      if (wave < 2) {
        f32x4 ax0 = {0.f,0.f,0.f,0.f}, ax1 = {0.f,0.f,0.f,0.f};
        const short8 xf = *(const short8*)&xsb[m16][wave * 32 + quad * 8];
        ax0 = __builtin_amdgcn_mfma_f32_16x16x32_bf16(xf, wfx[0], ax0, 0, 0, 0);
        ax1 = __builtin_amdgcn_mfma_f32_16x16x32_bf16(xf, wfx[1], ax1, 0, 0, 0);
        if (lane < 32) {
#pragma unroll
          for (int r = 0; r < 4; ++r) {
            partsX[wave][quad * 4 + r][m16]      = ax0[r];
            partsX[wave][quad * 4 + r][16 + m16] = ax1[r];
          }
        }
      }
    }
    __syncthreads();                                    // b1

    // ===== parallel epilogues: waves 0-3 = L0 step s | waves 4-7 = L1 step s-1
    if (wave < 4) {
      if (s < T_SZ) {
        float sH = 0.f;
#pragma unroll
        for (int w = 0; w < 8; ++w) sH += partsA[w][ech][cl];
        const float sX = partsX[0][ech][cl] + partsX[1][ech][cl];
        const float z = ((s == 0) ? c0i : c0f) + r0 * sH - r0 * m0 * uw0 + sX;
        const float h0prev = (s == 0) ? 0.f : (v2prev0 - m0) * r0 * g0c + be0c;
        const float v2 = fast_tanh(z) + h0prev;
        v2prev0 = v2;
        const unsigned vb = f2b(v2);
        *ep_lds = (unsigned short)vb;
        const unsigned v1s = __shfl_down(vb, 1), v2s = __shfl_down(vb, 2);
        ull* const pr = par ? prow1 : prow0;
        if (ispub)
          st_rlx(pr + jw, (ull)vb | ((ull)v1s << 16) |
                          (jw < 10 ? ((ull)v2s << 32) : 0ull) | ((ull)et << 48));
        float S = v2, Q = v2 * v2;
#pragma unroll
        for (int off = 16; off; off >>= 1) {
          S += __shfl_down(S, off, 32); Q += __shfl_down(Q, off, 32);
        }
        if (cl == 0) {
          st0[ech][p] = make_float2(S, Q);   // safe: all st0 reads hoisted pre-b1
          st_rlx(pr + 11, (ull)__float_as_uint(S) | ((ull)et << 32));
          st_rlx(pr + 12, (ull)__float_as_uint(Q) | ((ull)et << 32));
        }
      }
    } else if (s >= 1) {
      float sB = 0.f, sC = 0.f;
#pragma unroll
      for (int w = 0; w < 8; ++w) { sB += partsB[w][ech][cl]; sC += partsC[w][ech][cl]; }
      const float z = ((s == 1) ? c1i : c1f) + r0 * sC - r0 * m0 * uw1
                      + r1p * sB - r1p * m1p * uh1;
      const float h1prev = (s == 1) ? 0.f : (v2prev1 - m1p) * r1p * g1c + be1c;
      const float v2 = fast_tanh(z) + h1prev;
      v2prev1 = v2;
      const unsigned vb = f2b(v2);
      *ep_lds = (unsigned short)vb;
      const unsigned v1s = __shfl_down(vb, 1), v2s = __shfl_down(vb, 2);
      ull* const pr = par ? prow1 : prow0;
      if (ispub)
        st_rlx(pr + jw, (ull)vb | ((ull)v1s << 16) |
                        (jw < 10 ? ((ull)v2s << 32) : 0ull) | ((ull)et << 48));
      float S = v2, Q = v2 * v2;
#pragma unroll
      for (int off = 16; off; off >>= 1) {
        S += __shfl_down(S, off, 32); Q += __shfl_down(Q, off, 32);
      }
      if (cl == 0) {
        st1[ech][p] = make_float2(S, Q);
        st_rlx(pr + 11, (ull)__float_as_uint(S) | ((ull)et << 32));
        st_rlx(pr + 12, (ull)__float_as_uint(Q) | ((ull)et << 32));
      }
    }
    if (s == T_SZ) break;

    // x prefetch issue (consumed after b3 barrier next slot)
    float xv = 0.f;
    if (s + 1 < T_SZ) xv = *xptr;
    xptr += DD;

    // -------- tagged gather, BURST-PIPELINED: issue all -> check all -------
    {
      unsigned need = 0;
#pragma unroll
      for (int k = 0; k < 7; ++k)
        if (gtype[k] != 255 && (s > 0 || !gL1[k])) need |= 1u << k;
      while (need) {
        ull tv[7];
#pragma unroll
        for (int k = 0; k < 7; ++k)
          if ((need >> k) & 1u) tv[k] = ld_rlx(gsrc[k] + (par ? PAYW : 0));
        unsigned miss = 0;
#pragma unroll
        for (int k = 0; k < 7; ++k) {
          if ((need >> k) & 1u) {
            const ull u = tv[k];
            const bool ok = (gtype[k] < 2) ? ((u >> 48) == (ull)et)
                                           : ((u >> 32) == (ull)et);
            if (ok) {
              if (gtype[k] < 2) {
                unsigned short* d = (unsigned short*)gdst[k];
                d[0] = (unsigned short)u;
                d[1] = (unsigned short)(u >> 16);
                if (gtype[k] == 0) d[2] = (unsigned short)(u >> 32);
              } else {
                *(float*)gdst[k] = __uint_as_float((unsigned)u);
              }
            } else miss |= 1u << k;
          }
        }
        need = miss;
        if (need) __builtin_amdgcn_s_sleep(1);
      }
    }
    if (s + 1 < T_SZ) xsb[wave][lane] = f2b(xv);
    __syncthreads();                                    // b3
  }

  // ============ head (p==0 blocks): out = LN(v2_1^{T-1}).Wfc + bfc ========
  // v2_1^{T-1} published at slot T (par=0, tag T+1). Own block's share from
  // LDS (a1bf/st1, sealed by the barrier below); peers via tagged polls.
  if (p == 0) {
    __syncthreads();   // seal slot-T epilogue LDS writes (a1bf, st1)
    const int c = wave;   // wave handles chain c
    const unsigned etH = (unsigned)(T_SZ + 1);
    float Sp = 0.f, Qp = 0.f;
    if (lane < 30) {
      const int pl = 1 + (lane >> 1), which = lane & 1;
      const ull* a = pay + (((size_t)(group * NBLK + pl) * 2 + 1) * 2 + 0) * PAYW
                         + c * 13 + 11 + which;
      ull u;
      for (;;) { u = ld_rlx(a); if ((u >> 32) == (ull)etH) break; __builtin_amdgcn_s_sleep(4); }
      const float v = __uint_as_float((unsigned)u);
      if (which == 0) Sp = v; else Qp = v;
    }
#pragma unroll
    for (int off = 32; off; off >>= 1) { Sp += __shfl_down(Sp, off); Qp += __shfl_down(Qp, off); }
    const float2 own = st1[c][0];
    const float Stot = __shfl(Sp, 0) + own.x;
    const float Qtot = __shfl(Qp, 0) + own.y;
    const float m1 = Stot * (1.f / HH);
    const float r1 = __builtin_amdgcn_rsqf(Qtot * (1.f / HH) - m1 * m1 + 1e-5f);
    float o = 0.f;
    if (lane < 32)
      o = ((b2f(a1bf[c][lane]) - m1) * r1 * g1v[lane] + be1v[lane]) * wfc[lane];
#pragma unroll
    for (int it = 0; it < 3; ++it) {
      const int idx = lane + (it << 6);
      if (idx < 165) {                      // 15 peers x 11 payload words
        const int pl = 1 + idx / 11, w = idx - (pl - 1) * 11;
        const ull* a = pay + (((size_t)(group * NBLK + pl) * 2 + 1) * 2 + 0) * PAYW
                           + c * 13 + w;
        ull u;
        for (;;) { u = ld_rlx(a); if ((u >> 48) == (ull)etH) break; __builtin_amdgcn_s_sleep(4); }
#pragma unroll
        for (int q = 0; q < 3; ++q) {
          if (3 * w + q < 32) {
            const int col = pl * 32 + 3 * w + q;
            o += ((b2f((unsigned short)(u >> (16 * q))) - m1) * r1 * g1v[col]
                  + be1v[col]) * wfc[col];
          }
        }
      }
    }
#pragma unroll
    for (int off = 32; off; off >>= 1) o += __shfl_down(o, off);
    if (lane == 0) out[group * NCH + c] = o + bfc[0];
  }
}

extern "C" void kernel_launch(void* const* d_in, const int* in_sizes, int n_in,
                              void* d_out, int out_size, void* d_ws, size_t ws_size,
                              hipStream_t stream) {
  const float* x   = (const float*)d_in[0];
  const float* Wi0 = (const float*)d_in[1];
  const float* bi0 = (const float*)d_in[2];
  const float* Wh0 = (const float*)d_in[3];
  const float* bh0 = (const float*)d_in[4];
  const float* g0  = (const float*)d_in[5];
  const float* be0 = (const float*)d_in[6];
  const float* Wi1 = (const float*)d_in[7];
  const float* bi1 = (const float*)d_in[8];
  const float* Wh1 = (const float*)d_in[9];
  const float* bh1 = (const float*)d_in[10];
  const float* g1  = (const float*)d_in[11];
  const float* be1 = (const float*)d_in[12];
  const float* Wfc = (const float*)d_in[13];
  const float* bfc = (const float*)d_in[14];
  float* out = (float*)d_out;

  // ws: cvec 16KB | pay 852KB (tagged words, single copy)
  char* ws = (char*)d_ws;
  float* cvec = (float*)(ws);
  ull* pay    = (ull*)(ws + 16384);

  prep_kernel<<<256, 256, 0, stream>>>(Wh0, Wi1, Wh1, bi0, bh0, bi1, bh1,
                                       g0, be0, g1, be1, cvec, pay);
  rnn_mfma<<<256, 512, 0, stream>>>(x, Wi0, Wh0, Wi1, Wh1, cvec,
                                    g0, be0, g1, be1, Wfc, bfc,
                                    pay, out);
}